// Round 4
// baseline (1332.210 us; speedup 1.0000x reference)
//
#include <hip/hip_runtime.h>
#include <hip/hip_fp16.h>

#define BB 4096
#define NN 4096
#define RPB 2            // rows per block in k_K
#define RPI 8            // rows per block in k_it
#define NREP 2           // den replicas (atomic contention split)
#define NSLICE 11        // den slices: 0 = initial (v0=1), k = after iter k
#define DENF (NREP * NN) // floats per slice

// ---------------- mean(D) reduction + den init ----------------
// den layout: [NSLICE][NREP][NN]. slice0 = {cap, 0} so cap/denSum = 1 (v0).
__global__ __launch_bounds__(256) void k_mean(
        const float* __restrict__ Dt, float* __restrict__ dsum,
        float* __restrict__ den, const float* __restrict__ cap) {
    const int tid = blockIdx.x * blockDim.x + threadIdx.x;
    const int gs = gridDim.x * blockDim.x;
    for (int i = tid; i < NSLICE * DENF; i += gs)
        den[i] = (i < NN) ? cap[i] : 0.f;
    const float4* D4 = (const float4*)Dt;
    const int total4 = (BB * NN) / 4;
    float s = 0.f;
    for (int i = tid; i < total4; i += gs) {
        float4 d = D4[i];
        s += (d.x + d.y) + (d.z + d.w);
    }
    #pragma unroll
    for (int off = 32; off > 0; off >>= 1) s += __shfl_down(s, off, 64);
    __shared__ float ls[4];
    if ((threadIdx.x & 63) == 0) ls[threadIdx.x >> 6] = s;
    __syncthreads();
    if (threadIdx.x == 0) atomicAdd(dsum, (ls[0] + ls[1]) + (ls[2] + ls[3]));
}

// ---------------- K = exp(5*dot - 5*D/mean), fp16, fp16 lut ----------------
__global__ __launch_bounds__(256) void k_K(
        const int* __restrict__ users, const int* __restrict__ pois,
        const float* __restrict__ Dt, const float* __restrict__ poi_emb,
        const float* __restrict__ user_emb, const float* __restrict__ dsum,
        __half* __restrict__ K) {
    __shared__ __half slut[RPB][NN];      // 16 KB
    __shared__ float ues[RPB * 16];
    const int t = threadIdx.x;
    const int b0 = blockIdx.x * RPB;
    if (t < RPB * 16) {
        int r = t >> 4, d = t & 15;
        ues[t] = user_emb[(size_t)users[b0 + r] * 16 + d];
    }
    __syncthreads();
    float ue[RPB][16];
    #pragma unroll
    for (int r = 0; r < RPB; r++)
        #pragma unroll
        for (int d = 0; d < 16; d++) ue[r][d] = ues[r * 16 + d];

    const float4* pe4 = (const float4*)poi_emb;
    for (int j = t; j < NN; j += 256) {
        float4 p0 = pe4[j * 4 + 0];
        float4 p1 = pe4[j * 4 + 1];
        float4 p2 = pe4[j * 4 + 2];
        float4 p3 = pe4[j * 4 + 3];
        #pragma unroll
        for (int r = 0; r < RPB; r++) {
            float acc = p0.x*ue[r][0]  + p0.y*ue[r][1]  + p0.z*ue[r][2]  + p0.w*ue[r][3]
                      + p1.x*ue[r][4]  + p1.y*ue[r][5]  + p1.z*ue[r][6]  + p1.w*ue[r][7]
                      + p2.x*ue[r][8]  + p2.y*ue[r][9]  + p2.z*ue[r][10] + p2.w*ue[r][11]
                      + p3.x*ue[r][12] + p3.y*ue[r][13] + p3.z*ue[r][14] + p3.w*ue[r][15];
            slut[r][j] = __float2half(acc);
        }
    }
    __syncthreads();                       // lut read-only from here on
    const float cc = 5.0f * 16777216.0f / dsum[0];   // 5 / mean(D)
    #pragma unroll
    for (int r = 0; r < RPB; r++) {
        const size_t base = (size_t)(b0 + r) * NN;
        const int4*   p4 = (const int4*)(pois + base);
        const float4* d4 = (const float4*)(Dt + base);
        #pragma unroll
        for (int i = 0; i < NN / 4 / 256; i++) {     // 4
            const int q = t + i * 256;
            int4   ci = p4[q];
            float4 cd = d4[q];
            float k0 = __expf(5.0f * __half2float(slut[r][ci.x]) - cc * cd.x);
            float k1 = __expf(5.0f * __half2float(slut[r][ci.y]) - cc * cd.y);
            float k2 = __expf(5.0f * __half2float(slut[r][ci.z]) - cc * cd.z);
            float k3 = __expf(5.0f * __half2float(slut[r][ci.w]) - cc * cd.w);
            __half2* kw = (__half2*)&K[base + 4 * (size_t)q];
            kw[0] = __floats2half2_rn(k0, k1);
            kw[1] = __floats2half2_rn(k2, k3);
        }
    }
}

// ---------------- fp16 16-elem dot helper ----------------
__device__ __forceinline__ float dot16h(float4 h0, float4 h1,
        float4 wa0, float4 wa1, float4 wb0, float4 wb1) {
    const __half2* a = (const __half2*)&h0;
    const __half2* b = (const __half2*)&h1;
    float s = 0.f; float2 f;
    f = __half22float2(a[0]); s += f.x * wa0.x + f.y * wa0.y;
    f = __half22float2(a[1]); s += f.x * wa0.z + f.y * wa0.w;
    f = __half22float2(a[2]); s += f.x * wa1.x + f.y * wa1.y;
    f = __half22float2(a[3]); s += f.x * wa1.z + f.y * wa1.w;
    f = __half22float2(b[0]); s += f.x * wb0.x + f.y * wb0.y;
    f = __half22float2(b[1]); s += f.x * wb0.z + f.y * wb0.w;
    f = __half22float2(b[2]); s += f.x * wb1.x + f.y * wb1.y;
    f = __half22float2(b[3]); s += f.x * wb1.z + f.y * wb1.w;
    return s;
}

// ---------------- fused sinkhorn iteration ----------------
// Reads denPrev -> w = cap/denSum (== v_{k-1}); computes u_k for RPI rows;
// accumulates den_k[n] = sum_b K[b,n]*u_k[b] via atomics into denNext.
// Thread t owns cols {8t..8t+7} (group A) and {2048+8t..+7} (group B).
__global__ __launch_bounds__(256) void k_it(
        const __half* __restrict__ K, const float* __restrict__ cap,
        const float* __restrict__ denP, float* __restrict__ denN,
        float* __restrict__ u) {
    const int t = threadIdx.x;
    const int r0 = blockIdx.x * RPI;

    // w = cap / (denP rep0 + rep1) at this thread's 16 cols
    const float4* c4 = (const float4*)cap;
    const float4* d4 = (const float4*)denP;
    float4 ca0 = c4[2*t],       ca1 = c4[2*t+1];
    float4 cb0 = c4[512+2*t],   cb1 = c4[512+2*t+1];
    float4 da0 = d4[2*t],       da1 = d4[2*t+1];
    float4 db0 = d4[512+2*t],   db1 = d4[512+2*t+1];
    float4 ea0 = d4[1024+2*t],     ea1 = d4[1024+2*t+1];
    float4 eb0 = d4[1024+512+2*t], eb1 = d4[1024+512+2*t+1];
    float4 wa0 = make_float4(ca0.x/(da0.x+ea0.x), ca0.y/(da0.y+ea0.y),
                             ca0.z/(da0.z+ea0.z), ca0.w/(da0.w+ea0.w));
    float4 wa1 = make_float4(ca1.x/(da1.x+ea1.x), ca1.y/(da1.y+ea1.y),
                             ca1.z/(da1.z+ea1.z), ca1.w/(da1.w+ea1.w));
    float4 wb0 = make_float4(cb0.x/(db0.x+eb0.x), cb0.y/(db0.y+eb0.y),
                             cb0.z/(db0.z+eb0.z), cb0.w/(db0.w+eb0.w));
    float4 wb1 = make_float4(cb1.x/(db1.x+eb1.x), cb1.y/(db1.y+eb1.y),
                             cb1.z/(db1.z+eb1.z), cb1.w/(db1.w+eb1.w));

    // stream RPI rows (all loads issued before use)
    float4 h0[RPI], h1[RPI];
    #pragma unroll
    for (int r = 0; r < RPI; r++) {
        const float4* rr = (const float4*)(K + (size_t)(r0 + r) * NN);
        h0[r] = rr[t];
        h1[r] = rr[256 + t];
    }
    float acc[RPI];
    #pragma unroll
    for (int r = 0; r < RPI; r++) acc[r] = dot16h(h0[r], h1[r], wa0, wa1, wb0, wb1);
    #pragma unroll
    for (int off = 32; off > 0; off >>= 1)
        #pragma unroll
        for (int r = 0; r < RPI; r++) acc[r] += __shfl_down(acc[r], off, 64);
    __shared__ float ls[4][RPI];
    __shared__ float us[RPI];
    if ((t & 63) == 0)
        #pragma unroll
        for (int r = 0; r < RPI; r++) ls[t >> 6][r] = acc[r];
    __syncthreads();
    if (t < RPI) {
        float uu = 1.0f / ((ls[0][t] + ls[1][t]) + (ls[2][t] + ls[3][t]));
        us[t] = uu;
        u[r0 + t] = uu;
    }
    __syncthreads();

    // column partials: den[n] += K[b,n]*u[b] over this block's rows
    float4 A0 = make_float4(0,0,0,0), A1 = A0, B0 = A0, B1 = A0;
    #pragma unroll
    for (int r = 0; r < RPI; r++) {
        const float ur = us[r];
        const __half2* a = (const __half2*)&h0[r];
        const __half2* b = (const __half2*)&h1[r];
        float2 f;
        f = __half22float2(a[0]); A0.x += ur*f.x; A0.y += ur*f.y;
        f = __half22float2(a[1]); A0.z += ur*f.x; A0.w += ur*f.y;
        f = __half22float2(a[2]); A1.x += ur*f.x; A1.y += ur*f.y;
        f = __half22float2(a[3]); A1.z += ur*f.x; A1.w += ur*f.y;
        f = __half22float2(b[0]); B0.x += ur*f.x; B0.y += ur*f.y;
        f = __half22float2(b[1]); B0.z += ur*f.x; B0.w += ur*f.y;
        f = __half22float2(b[2]); B1.x += ur*f.x; B1.y += ur*f.y;
        f = __half22float2(b[3]); B1.z += ur*f.x; B1.w += ur*f.y;
    }
    float* dn = denN + (blockIdx.x & (NREP - 1)) * NN;
    const int cA = 8 * t, cB = 2048 + 8 * t;
    atomicAdd(&dn[cA+0], A0.x); atomicAdd(&dn[cA+1], A0.y);
    atomicAdd(&dn[cA+2], A0.z); atomicAdd(&dn[cA+3], A0.w);
    atomicAdd(&dn[cA+4], A1.x); atomicAdd(&dn[cA+5], A1.y);
    atomicAdd(&dn[cA+6], A1.z); atomicAdd(&dn[cA+7], A1.w);
    atomicAdd(&dn[cB+0], B0.x); atomicAdd(&dn[cB+1], B0.y);
    atomicAdd(&dn[cB+2], B0.z); atomicAdd(&dn[cB+3], B0.w);
    atomicAdd(&dn[cB+4], B1.x); atomicAdd(&dn[cB+5], B1.y);
    atomicAdd(&dn[cB+6], B1.z); atomicAdd(&dn[cB+7], B1.w);
}

// ---------------- P = K * u[b] * cap[n]/den10[n], grid-stride ----------------
__global__ __launch_bounds__(256) void k_P_h(
        const __half* __restrict__ K, const float* __restrict__ u,
        const float* __restrict__ cap, const float* __restrict__ denF,
        float* __restrict__ P) {
    const int stride = gridDim.x * 256;
    const float4* c4 = (const float4*)cap;
    const float4* d4 = (const float4*)denF;
    for (int i = blockIdx.x * 256 + threadIdx.x; i < BB * NN / 8; i += stride) {
        const int e = i * 8;
        const int b = e >> 12;
        const int col = e & 4095;           // multiple of 8
        const int q = col >> 2;
        float4 raw = ((const float4*)K)[i];
        const __half2* h = (const __half2*)&raw;
        const float ub = u[b];
        float4 c0 = c4[q], c1 = c4[q+1];
        float4 d0 = d4[q], d1 = d4[q+1];
        float4 e0 = d4[1024+q], e1 = d4[1024+q+1];
        float4 v0 = make_float4(c0.x/(d0.x+e0.x), c0.y/(d0.y+e0.y),
                                c0.z/(d0.z+e0.z), c0.w/(d0.w+e0.w));
        float4 v1 = make_float4(c1.x/(d1.x+e1.x), c1.y/(d1.y+e1.y),
                                c1.z/(d1.z+e1.z), c1.w/(d1.w+e1.w));
        float2 f0 = __half22float2(h[0]);
        float2 f1 = __half22float2(h[1]);
        float2 f2 = __half22float2(h[2]);
        float2 f3 = __half22float2(h[3]);
        ((float4*)P)[e >> 2]       = make_float4(f0.x*ub*v0.x, f0.y*ub*v0.y,
                                                 f1.x*ub*v0.z, f1.y*ub*v0.w);
        ((float4*)P)[(e >> 2) + 1] = make_float4(f2.x*ub*v1.x, f2.y*ub*v1.y,
                                                 f3.x*ub*v1.z, f3.y*ub*v1.w);
    }
}

extern "C" void kernel_launch(void* const* d_in, const int* in_sizes, int n_in,
                              void* d_out, int out_size, void* d_ws, size_t ws_size,
                              hipStream_t stream) {
    const int*   users    = (const int*)d_in[0];
    const int*   pois     = (const int*)d_in[1];
    const float* Dt       = (const float*)d_in[2];
    const float* poi_emb  = (const float*)d_in[3];
    const float* user_emb = (const float*)d_in[4];
    const float* cap      = (const float*)d_in[5];
    float* out = (float*)d_out;

    float*  wsf  = (float*)d_ws;
    float*  dsum = wsf;                         // [64]
    float*  u    = wsf + 64;                    // [BB]
    float*  den  = wsf + 64 + BB;               // [NSLICE*NREP*NN] = 352 KB
    __half* Kh   = (__half*)(den + NSLICE * DENF);   // [BB*NN] fp16 = 33.5 MB

    hipMemsetAsync(dsum, 0, sizeof(float), stream);
    k_mean<<<2048, 256, 0, stream>>>(Dt, dsum, den, cap);
    k_K<<<BB / RPB, 256, 0, stream>>>(users, pois, Dt, poi_emb, user_emb, dsum, Kh);
    for (int it = 0; it < 10; it++) {
        k_it<<<BB / RPI, 256, 0, stream>>>(Kh, cap, den + it * DENF,
                                           den + (it + 1) * DENF, u);
    }
    k_P_h<<<2048, 256, 0, stream>>>(Kh, u, cap, den + 10 * DENF, out);
}

// Round 5
// 395.078 us; speedup vs baseline: 3.3720x; 3.3720x over previous
//
#include <hip/hip_runtime.h>
#include <hip/hip_fp16.h>

#define BB 4096
#define NN 4096
#define RPB 2            // rows per block in k_K
#define RPI 8            // rows per block in k_it / k_P
#define NBLK (BB / RPI)  // 512 row-blocks

// XCD-contiguous swizzle: round-robin dispatch puts bid%8 on XCD bid%8;
// this makes XCD x own row-blocks [x*64, (x+1)*64) = rows [x*512,...) = 4 MiB panel.
__device__ __forceinline__ int swz(int bid) { return (bid & 7) * 64 + (bid >> 3); }

// ---------------- mean(D) reduction + v=1 init ----------------
__global__ __launch_bounds__(256) void k_mean(
        const float* __restrict__ Dt, float* __restrict__ dsum,
        float* __restrict__ v) {
    const int tid = blockIdx.x * blockDim.x + threadIdx.x;
    const int gs = gridDim.x * blockDim.x;
    if (tid < NN) v[tid] = 1.0f;
    const float4* D4 = (const float4*)Dt;
    const int total4 = (BB * NN) / 4;
    float s = 0.f;
    for (int i = tid; i < total4; i += gs) {
        float4 d = D4[i];
        s += (d.x + d.y) + (d.z + d.w);
    }
    #pragma unroll
    for (int off = 32; off > 0; off >>= 1) s += __shfl_down(s, off, 64);
    __shared__ float ls[4];
    if ((threadIdx.x & 63) == 0) ls[threadIdx.x >> 6] = s;
    __syncthreads();
    if (threadIdx.x == 0) atomicAdd(dsum, (ls[0] + ls[1]) + (ls[2] + ls[3]));
}

// ---------------- K = exp(5*dot - 5*D/mean), fp16, fp16 lut ----------------
__global__ __launch_bounds__(256) void k_K(
        const int* __restrict__ users, const int* __restrict__ pois,
        const float* __restrict__ Dt, const float* __restrict__ poi_emb,
        const float* __restrict__ user_emb, const float* __restrict__ dsum,
        __half* __restrict__ K) {
    __shared__ __half slut[RPB][NN];      // 16 KB
    __shared__ float ues[RPB * 16];
    const int t = threadIdx.x;
    const int b0 = blockIdx.x * RPB;
    if (t < RPB * 16) {
        int r = t >> 4, d = t & 15;
        ues[t] = user_emb[(size_t)users[b0 + r] * 16 + d];
    }
    __syncthreads();
    float ue[RPB][16];
    #pragma unroll
    for (int r = 0; r < RPB; r++)
        #pragma unroll
        for (int d = 0; d < 16; d++) ue[r][d] = ues[r * 16 + d];

    const float4* pe4 = (const float4*)poi_emb;
    for (int j = t; j < NN; j += 256) {
        float4 p0 = pe4[j * 4 + 0];
        float4 p1 = pe4[j * 4 + 1];
        float4 p2 = pe4[j * 4 + 2];
        float4 p3 = pe4[j * 4 + 3];
        #pragma unroll
        for (int r = 0; r < RPB; r++) {
            float acc = p0.x*ue[r][0]  + p0.y*ue[r][1]  + p0.z*ue[r][2]  + p0.w*ue[r][3]
                      + p1.x*ue[r][4]  + p1.y*ue[r][5]  + p1.z*ue[r][6]  + p1.w*ue[r][7]
                      + p2.x*ue[r][8]  + p2.y*ue[r][9]  + p2.z*ue[r][10] + p2.w*ue[r][11]
                      + p3.x*ue[r][12] + p3.y*ue[r][13] + p3.z*ue[r][14] + p3.w*ue[r][15];
            slut[r][j] = __float2half(acc);
        }
    }
    __syncthreads();                       // lut read-only from here on
    const float cc = 5.0f * 16777216.0f / dsum[0];   // 5 / mean(D)
    #pragma unroll
    for (int r = 0; r < RPB; r++) {
        const size_t base = (size_t)(b0 + r) * NN;
        const int4*   p4 = (const int4*)(pois + base);
        const float4* d4 = (const float4*)(Dt + base);
        #pragma unroll
        for (int i = 0; i < NN / 4 / 256; i++) {     // 4
            const int q = t + i * 256;
            int4   ci = p4[q];
            float4 cd = d4[q];
            float k0 = __expf(5.0f * __half2float(slut[r][ci.x]) - cc * cd.x);
            float k1 = __expf(5.0f * __half2float(slut[r][ci.y]) - cc * cd.y);
            float k2 = __expf(5.0f * __half2float(slut[r][ci.z]) - cc * cd.z);
            float k3 = __expf(5.0f * __half2float(slut[r][ci.w]) - cc * cd.w);
            __half2* kw = (__half2*)&K[base + 4 * (size_t)q];
            kw[0] = __floats2half2_rn(k0, k1);
            kw[1] = __floats2half2_rn(k2, k3);
        }
    }
}

// ---------------- fp16 16-elem dot helper ----------------
__device__ __forceinline__ float dot16h(float4 h0, float4 h1,
        float4 wa0, float4 wa1, float4 wb0, float4 wb1) {
    const __half2* a = (const __half2*)&h0;
    const __half2* b = (const __half2*)&h1;
    float s = 0.f; float2 f;
    f = __half22float2(a[0]); s += f.x * wa0.x + f.y * wa0.y;
    f = __half22float2(a[1]); s += f.x * wa0.z + f.y * wa0.w;
    f = __half22float2(a[2]); s += f.x * wa1.x + f.y * wa1.y;
    f = __half22float2(a[3]); s += f.x * wa1.z + f.y * wa1.w;
    f = __half22float2(b[0]); s += f.x * wb0.x + f.y * wb0.y;
    f = __half22float2(b[1]); s += f.x * wb0.z + f.y * wb0.w;
    f = __half22float2(b[2]); s += f.x * wb1.x + f.y * wb1.y;
    f = __half22float2(b[3]); s += f.x * wb1.z + f.y * wb1.w;
    return s;
}

// ---------------- fused sinkhorn iteration (no atomics) ----------------
// Reads v (= v_{k-1}); computes u_k for its RPI rows; writes per-block
// column partials sum_b K[b,n]*u_k[b] to part[sb][n] (coalesced, exclusive).
// Thread t owns cols {8t..8t+7} (A) and {2048+8t..+7} (B).
__global__ __launch_bounds__(256) void k_it(
        const __half* __restrict__ K, const float* __restrict__ v,
        float* __restrict__ part, float* __restrict__ u) {
    const int t = threadIdx.x;
    const int sb = swz(blockIdx.x);
    const int r0 = sb * RPI;

    const float4* w4 = (const float4*)v;
    float4 wa0 = w4[2*t],     wa1 = w4[2*t+1];
    float4 wb0 = w4[512+2*t], wb1 = w4[512+2*t+1];

    // stream RPI rows (all loads issued before use)
    float4 h0[RPI], h1[RPI];
    #pragma unroll
    for (int r = 0; r < RPI; r++) {
        const float4* rr = (const float4*)(K + (size_t)(r0 + r) * NN);
        h0[r] = rr[t];
        h1[r] = rr[256 + t];
    }
    float acc[RPI];
    #pragma unroll
    for (int r = 0; r < RPI; r++) acc[r] = dot16h(h0[r], h1[r], wa0, wa1, wb0, wb1);
    #pragma unroll
    for (int off = 32; off > 0; off >>= 1)
        #pragma unroll
        for (int r = 0; r < RPI; r++) acc[r] += __shfl_down(acc[r], off, 64);
    __shared__ float ls[4][RPI];
    __shared__ float us[RPI];
    if ((t & 63) == 0)
        #pragma unroll
        for (int r = 0; r < RPI; r++) ls[t >> 6][r] = acc[r];
    __syncthreads();
    if (t < RPI) {
        float uu = 1.0f / ((ls[0][t] + ls[1][t]) + (ls[2][t] + ls[3][t]));
        us[t] = uu;
        u[r0 + t] = uu;
    }
    __syncthreads();

    // column partials over this block's rows (registers only)
    float4 A0 = make_float4(0,0,0,0), A1 = A0, B0 = A0, B1 = A0;
    #pragma unroll
    for (int r = 0; r < RPI; r++) {
        const float ur = us[r];
        const __half2* a = (const __half2*)&h0[r];
        const __half2* b = (const __half2*)&h1[r];
        float2 f;
        f = __half22float2(a[0]); A0.x += ur*f.x; A0.y += ur*f.y;
        f = __half22float2(a[1]); A0.z += ur*f.x; A0.w += ur*f.y;
        f = __half22float2(a[2]); A1.x += ur*f.x; A1.y += ur*f.y;
        f = __half22float2(a[3]); A1.z += ur*f.x; A1.w += ur*f.y;
        f = __half22float2(b[0]); B0.x += ur*f.x; B0.y += ur*f.y;
        f = __half22float2(b[1]); B0.z += ur*f.x; B0.w += ur*f.y;
        f = __half22float2(b[2]); B1.x += ur*f.x; B1.y += ur*f.y;
        f = __half22float2(b[3]); B1.z += ur*f.x; B1.w += ur*f.y;
    }
    float4* p4 = (float4*)(part + (size_t)sb * NN);
    p4[2*t]       = A0;
    p4[2*t+1]     = A1;
    p4[512+2*t]   = B0;
    p4[512+2*t+1] = B1;
}

// ---------------- v[n] = cap[n] / sum_sb part[sb][n] ----------------
// 128 blocks; block g owns n4 stripe [g*8, g*8+8) (32 cols).
__global__ __launch_bounds__(256) void k_red(
        const float* __restrict__ part, const float* __restrict__ cap,
        float* __restrict__ v) {
    const int t = threadIdx.x;
    const int g = blockIdx.x;
    const int j = t & 7;     // n4 offset in stripe
    const int s = t >> 3;    // 0..31 slice
    const float4* p4 = (const float4*)part;
    float4 a = make_float4(0,0,0,0);
    #pragma unroll
    for (int i = 0; i < NBLK / 32; i++) {          // 16
        float4 x = p4[(size_t)(s + 32 * i) * (NN/4) + g * 8 + j];
        a.x += x.x; a.y += x.y; a.z += x.z; a.w += x.w;
    }
    __shared__ float4 red[32][8];
    red[s][j] = a;
    __syncthreads();
    if (t < 8) {
        float4 b = red[0][t];
        #pragma unroll
        for (int s2 = 1; s2 < 32; s2++) {
            float4 x = red[s2][t];
            b.x += x.x; b.y += x.y; b.z += x.z; b.w += x.w;
        }
        float4 cc = ((const float4*)cap)[g * 8 + t];
        ((float4*)v)[g * 8 + t] =
            make_float4(cc.x / b.x, cc.y / b.y, cc.z / b.z, cc.w / b.w);
    }
}

// ---------------- P = K * u[b] * v[n], same row-panel swizzle ----------------
__global__ __launch_bounds__(256) void k_P(
        const __half* __restrict__ K, const float* __restrict__ u,
        const float* __restrict__ v, float* __restrict__ P) {
    const int t = threadIdx.x;
    const int sb = swz(blockIdx.x);
    const int r0 = sb * RPI;
    const float4* v4 = (const float4*)v;
    float4 va0 = v4[2*t],     va1 = v4[2*t+1];
    float4 vb0 = v4[512+2*t], vb1 = v4[512+2*t+1];
    #pragma unroll 2
    for (int r = 0; r < RPI; r++) {
        const int b = r0 + r;
        const float ub = u[b];
        const size_t base = (size_t)b * NN;
        const float4* k4 = (const float4*)(K + base);
        float4 raw0 = k4[t], raw1 = k4[256 + t];
        const __half2* ha = (const __half2*)&raw0;
        const __half2* hb = (const __half2*)&raw1;
        float2 f0 = __half22float2(ha[0]);
        float2 f1 = __half22float2(ha[1]);
        float2 f2 = __half22float2(ha[2]);
        float2 f3 = __half22float2(ha[3]);
        float2 g0 = __half22float2(hb[0]);
        float2 g1 = __half22float2(hb[1]);
        float2 g2 = __half22float2(hb[2]);
        float2 g3 = __half22float2(hb[3]);
        float4* P4 = (float4*)(P + base);
        P4[2*t]       = make_float4(f0.x*ub*va0.x, f0.y*ub*va0.y, f1.x*ub*va0.z, f1.y*ub*va0.w);
        P4[2*t+1]     = make_float4(f2.x*ub*va1.x, f2.y*ub*va1.y, f3.x*ub*va1.z, f3.y*ub*va1.w);
        P4[512+2*t]   = make_float4(g0.x*ub*vb0.x, g0.y*ub*vb0.y, g1.x*ub*vb0.z, g1.y*ub*vb0.w);
        P4[512+2*t+1] = make_float4(g2.x*ub*vb1.x, g2.y*ub*vb1.y, g3.x*ub*vb1.z, g3.y*ub*vb1.w);
    }
}

extern "C" void kernel_launch(void* const* d_in, const int* in_sizes, int n_in,
                              void* d_out, int out_size, void* d_ws, size_t ws_size,
                              hipStream_t stream) {
    const int*   users    = (const int*)d_in[0];
    const int*   pois     = (const int*)d_in[1];
    const float* Dt       = (const float*)d_in[2];
    const float* poi_emb  = (const float*)d_in[3];
    const float* user_emb = (const float*)d_in[4];
    const float* cap      = (const float*)d_in[5];
    float* out = (float*)d_out;

    float*  wsf  = (float*)d_ws;
    float*  dsum = wsf;                         // [64]
    float*  u    = wsf + 64;                    // [BB]
    float*  v    = wsf + 64 + BB;               // [NN]
    __half* Kh   = (__half*)(wsf + 64 + BB + NN);   // [BB*NN] fp16 = 33.5 MB
    float*  part = (float*)d_out;               // [NBLK*NN] = 8 MB; dead before k_P

    hipMemsetAsync(dsum, 0, sizeof(float), stream);
    k_mean<<<2048, 256, 0, stream>>>(Dt, dsum, v);
    k_K<<<BB / RPB, 256, 0, stream>>>(users, pois, Dt, poi_emb, user_emb, dsum, Kh);
    for (int it = 0; it < 10; it++) {
        k_it<<<NBLK, 256, 0, stream>>>(Kh, v, part, u);
        k_red<<<128, 256, 0, stream>>>(part, cap, v);
    }
    k_P<<<NBLK, 256, 0, stream>>>(Kh, u, v, out);
}

// Round 6
// 386.643 us; speedup vs baseline: 3.4456x; 1.0218x over previous
//
#include <hip/hip_runtime.h>
#include <hip/hip_fp16.h>

#define BB 4096
#define NN 4096
#define RPB 4            // rows per block in k_K
#define RPI 8            // rows per block in k_it / k_P
#define NBLK (BB / RPI)  // 512 row-blocks

// XCD-contiguous swizzle: round-robin dispatch puts bid%8 on XCD bid%8;
// XCD x then owns rows [x*512, x*512+512) = one 4 MiB K panel.
__device__ __forceinline__ int swz(int bid) { return (bid & 7) * 64 + (bid >> 3); }

// ---------------- mean(D) reduction + v=1 init ----------------
__global__ __launch_bounds__(256) void k_mean(
        const float* __restrict__ Dt, float* __restrict__ dsum,
        float* __restrict__ v) {
    const int tid = blockIdx.x * blockDim.x + threadIdx.x;
    const int gs = gridDim.x * blockDim.x;
    if (tid < NN) v[tid] = 1.0f;
    const float4* D4 = (const float4*)Dt;
    const int total4 = (BB * NN) / 4;
    float s = 0.f;
    for (int i = tid; i < total4; i += gs) {
        float4 d = D4[i];
        s += (d.x + d.y) + (d.z + d.w);
    }
    #pragma unroll
    for (int off = 32; off > 0; off >>= 1) s += __shfl_down(s, off, 64);
    __shared__ float ls[4];
    if ((threadIdx.x & 63) == 0) ls[threadIdx.x >> 6] = s;
    __syncthreads();
    if (threadIdx.x == 0) atomicAdd(dsum, (ls[0] + ls[1]) + (ls[2] + ls[3]));
}

// ---------------- K = exp(5*dot - 5*D/mean), fp16, fp16 lut ----------------
__global__ __launch_bounds__(256) void k_K(
        const int* __restrict__ users, const int* __restrict__ pois,
        const float* __restrict__ Dt, const float* __restrict__ poi_emb,
        const float* __restrict__ user_emb, const float* __restrict__ dsum,
        __half* __restrict__ K) {
    __shared__ __half slut[RPB][NN];      // 32 KB -> 4-5 blocks/CU
    __shared__ float ues[RPB * 16];
    const int t = threadIdx.x;
    const int b0 = blockIdx.x * RPB;
    if (t < RPB * 16) {
        int r = t >> 4, d = t & 15;
        ues[t] = user_emb[(size_t)users[b0 + r] * 16 + d];
    }
    __syncthreads();
    float ue[RPB][16];
    #pragma unroll
    for (int r = 0; r < RPB; r++)
        #pragma unroll
        for (int d = 0; d < 16; d++) ue[r][d] = ues[r * 16 + d];

    const float4* pe4 = (const float4*)poi_emb;
    for (int j = t; j < NN; j += 256) {
        float4 p0 = pe4[j * 4 + 0];
        float4 p1 = pe4[j * 4 + 1];
        float4 p2 = pe4[j * 4 + 2];
        float4 p3 = pe4[j * 4 + 3];
        #pragma unroll
        for (int r = 0; r < RPB; r++) {
            float acc = p0.x*ue[r][0]  + p0.y*ue[r][1]  + p0.z*ue[r][2]  + p0.w*ue[r][3]
                      + p1.x*ue[r][4]  + p1.y*ue[r][5]  + p1.z*ue[r][6]  + p1.w*ue[r][7]
                      + p2.x*ue[r][8]  + p2.y*ue[r][9]  + p2.z*ue[r][10] + p2.w*ue[r][11]
                      + p3.x*ue[r][12] + p3.y*ue[r][13] + p3.z*ue[r][14] + p3.w*ue[r][15];
            slut[r][j] = __float2half(acc);
        }
    }
    __syncthreads();                       // lut read-only from here on
    const float cc = 5.0f * 16777216.0f / dsum[0];   // 5 / mean(D)
    #pragma unroll
    for (int r = 0; r < RPB; r++) {
        const size_t base = (size_t)(b0 + r) * NN;
        const int4*   p4 = (const int4*)(pois + base);
        const float4* d4 = (const float4*)(Dt + base);
        #pragma unroll
        for (int i = 0; i < NN / 4 / 256; i++) {     // 4
            const int q = t + i * 256;
            int4   ci = p4[q];
            float4 cd = d4[q];
            float k0 = __expf(5.0f * __half2float(slut[r][ci.x]) - cc * cd.x);
            float k1 = __expf(5.0f * __half2float(slut[r][ci.y]) - cc * cd.y);
            float k2 = __expf(5.0f * __half2float(slut[r][ci.z]) - cc * cd.z);
            float k3 = __expf(5.0f * __half2float(slut[r][ci.w]) - cc * cd.w);
            __half2* kw = (__half2*)&K[base + 4 * (size_t)q];
            kw[0] = __floats2half2_rn(k0, k1);
            kw[1] = __floats2half2_rn(k2, k3);
        }
    }
}

// ---------------- fused sinkhorn iteration (512 threads, no atomics) -------
// Thread t owns cols [8t, 8t+8): one float4 (8 fp16) per row. All 8 row
// loads live in 32 VGPRs -> fully in flight. 8 waves/block, 16 waves/CU.
__global__ __launch_bounds__(512) void k_it(
        const __half* __restrict__ K, const float* __restrict__ v,
        float* __restrict__ part, float* __restrict__ u) {
    const int t = threadIdx.x;            // 0..511
    const int sb = swz(blockIdx.x);
    const int r0 = sb * RPI;

    const float4* w4 = (const float4*)v;
    float4 w0 = w4[2 * t], w1 = w4[2 * t + 1];

    float4 h[RPI];
    #pragma unroll
    for (int r = 0; r < RPI; r++)
        h[r] = ((const float4*)(K + (size_t)(r0 + r) * NN))[t];

    float acc[RPI];
    #pragma unroll
    for (int r = 0; r < RPI; r++) {
        const __half2* a = (const __half2*)&h[r];
        float2 f; float s = 0.f;
        f = __half22float2(a[0]); s += f.x * w0.x + f.y * w0.y;
        f = __half22float2(a[1]); s += f.x * w0.z + f.y * w0.w;
        f = __half22float2(a[2]); s += f.x * w1.x + f.y * w1.y;
        f = __half22float2(a[3]); s += f.x * w1.z + f.y * w1.w;
        acc[r] = s;
    }
    #pragma unroll
    for (int off = 32; off > 0; off >>= 1)
        #pragma unroll
        for (int r = 0; r < RPI; r++) acc[r] += __shfl_down(acc[r], off, 64);
    __shared__ float ls[8][RPI];
    __shared__ float us[RPI];
    if ((t & 63) == 0)
        #pragma unroll
        for (int r = 0; r < RPI; r++) ls[t >> 6][r] = acc[r];
    __syncthreads();
    if (t < RPI) {
        float s = 0.f;
        #pragma unroll
        for (int wv = 0; wv < 8; wv++) s += ls[wv][t];
        float uu = 1.0f / s;
        us[t] = uu;
        u[r0 + t] = uu;
    }
    __syncthreads();

    // column partials over this block's rows (registers only)
    float4 A0 = make_float4(0, 0, 0, 0), A1 = A0;
    #pragma unroll
    for (int r = 0; r < RPI; r++) {
        const float ur = us[r];
        const __half2* a = (const __half2*)&h[r];
        float2 f;
        f = __half22float2(a[0]); A0.x += ur * f.x; A0.y += ur * f.y;
        f = __half22float2(a[1]); A0.z += ur * f.x; A0.w += ur * f.y;
        f = __half22float2(a[2]); A1.x += ur * f.x; A1.y += ur * f.y;
        f = __half22float2(a[3]); A1.z += ur * f.x; A1.w += ur * f.y;
    }
    float4* p4 = (float4*)(part + (size_t)sb * NN);
    p4[2 * t]     = A0;
    p4[2 * t + 1] = A1;
}

// ---------------- v[n] = cap[n] / sum_sb part[sb][n] ----------------
__global__ __launch_bounds__(256) void k_red(
        const float* __restrict__ part, const float* __restrict__ cap,
        float* __restrict__ v) {
    const int t = threadIdx.x;
    const int g = blockIdx.x;
    const int j = t & 7;     // n4 offset in stripe
    const int s = t >> 3;    // 0..31 slice
    const float4* p4 = (const float4*)part;
    float4 a = make_float4(0, 0, 0, 0);
    #pragma unroll
    for (int i = 0; i < NBLK / 32; i++) {          // 16
        float4 x = p4[(size_t)(s + 32 * i) * (NN / 4) + g * 8 + j];
        a.x += x.x; a.y += x.y; a.z += x.z; a.w += x.w;
    }
    __shared__ float4 red[32][8];
    red[s][j] = a;
    __syncthreads();
    if (t < 8) {
        float4 b = red[0][t];
        #pragma unroll
        for (int s2 = 1; s2 < 32; s2++) {
            float4 x = red[s2][t];
            b.x += x.x; b.y += x.y; b.z += x.z; b.w += x.w;
        }
        float4 cc = ((const float4*)cap)[g * 8 + t];
        ((float4*)v)[g * 8 + t] =
            make_float4(cc.x / b.x, cc.y / b.y, cc.z / b.z, cc.w / b.w);
    }
}

// ---------------- P = K * u[b] * v[n], same row-panel swizzle ----------------
__global__ __launch_bounds__(256) void k_P(
        const __half* __restrict__ K, const float* __restrict__ u,
        const float* __restrict__ v, float* __restrict__ P) {
    const int t = threadIdx.x;
    const int sb = swz(blockIdx.x);
    const int r0 = sb * RPI;
    const float4* v4 = (const float4*)v;
    float4 va0 = v4[2 * t],       va1 = v4[2 * t + 1];
    float4 vb0 = v4[512 + 2 * t], vb1 = v4[512 + 2 * t + 1];
    #pragma unroll 2
    for (int r = 0; r < RPI; r++) {
        const int b = r0 + r;
        const float ub = u[b];
        const size_t base = (size_t)b * NN;
        const float4* k4 = (const float4*)(K + base);
        float4 raw0 = k4[t], raw1 = k4[256 + t];
        const __half2* ha = (const __half2*)&raw0;
        const __half2* hb = (const __half2*)&raw1;
        float2 f0 = __half22float2(ha[0]);
        float2 f1 = __half22float2(ha[1]);
        float2 f2 = __half22float2(ha[2]);
        float2 f3 = __half22float2(ha[3]);
        float2 g0 = __half22float2(hb[0]);
        float2 g1 = __half22float2(hb[1]);
        float2 g2 = __half22float2(hb[2]);
        float2 g3 = __half22float2(hb[3]);
        float4* P4 = (float4*)(P + base);
        P4[2*t]       = make_float4(f0.x*ub*va0.x, f0.y*ub*va0.y, f1.x*ub*va0.z, f1.y*ub*va0.w);
        P4[2*t+1]     = make_float4(f2.x*ub*va1.x, f2.y*ub*va1.y, f3.x*ub*va1.z, f3.y*ub*va1.w);
        P4[512+2*t]   = make_float4(g0.x*ub*vb0.x, g0.y*ub*vb0.y, g1.x*ub*vb0.z, g1.y*ub*vb0.w);
        P4[512+2*t+1] = make_float4(g2.x*ub*vb1.x, g2.y*ub*vb1.y, g3.x*ub*vb1.z, g3.y*ub*vb1.w);
    }
}

extern "C" void kernel_launch(void* const* d_in, const int* in_sizes, int n_in,
                              void* d_out, int out_size, void* d_ws, size_t ws_size,
                              hipStream_t stream) {
    const int*   users    = (const int*)d_in[0];
    const int*   pois     = (const int*)d_in[1];
    const float* Dt       = (const float*)d_in[2];
    const float* poi_emb  = (const float*)d_in[3];
    const float* user_emb = (const float*)d_in[4];
    const float* cap      = (const float*)d_in[5];
    float* out = (float*)d_out;

    float*  wsf  = (float*)d_ws;
    float*  dsum = wsf;                         // [64]
    float*  u    = wsf + 64;                    // [BB]
    float*  v    = wsf + 64 + BB;               // [NN]
    __half* Kh   = (__half*)(wsf + 64 + BB + NN);   // [BB*NN] fp16 = 33.5 MB
    float*  part = (float*)d_out;               // [NBLK*NN] = 8 MB; dead before k_P

    hipMemsetAsync(dsum, 0, sizeof(float), stream);
    k_mean<<<2048, 256, 0, stream>>>(Dt, dsum, v);
    k_K<<<BB / RPB, 256, 0, stream>>>(users, pois, Dt, poi_emb, user_emb, dsum, Kh);
    for (int it = 0; it < 10; it++) {
        k_it<<<NBLK, 512, 0, stream>>>(Kh, v, part, u);
        k_red<<<128, 256, 0, stream>>>(part, cap, v);
    }
    k_P<<<NBLK, 256, 0, stream>>>(Kh, u, v, out);
}